// Round 6
// baseline (335.481 us; speedup 1.0000x reference)
//
#include <hip/hip_runtime.h>
#include <math.h>

#define B_    32
#define S_    4096
#define DIN_  256
#define D_    256
#define T_    256
#define NB_   4
#define K_    5
#define EPS_  1e-5f
#define ROWS_ (B_ * T_)   // 8192

#define ORS_  16          // owned rows per block
#define CR_   32          // computed rows = owned + 8 halo each side
#define BR_   36          // buf0 rows = CR_ + 2 conv-pad rows each side
#define SEGS_ 16          // T_/ORS_
#define ASTR  264         // bf16 row stride in shorts (528 B, 16B-aligned)
#define HSTR  264         // h_lds row stride in floats (1056 B, 16B-aligned)

typedef short  shortx8 __attribute__((ext_vector_type(8)));
typedef float  floatx4 __attribute__((ext_vector_type(4)));

__device__ __forceinline__ unsigned short f2bf(float f) {
    unsigned int u = __float_as_uint(f);
    u += 0x7FFFu + ((u >> 16) & 1u);
    return (unsigned short)(u >> 16);
}
__device__ __forceinline__ float bf2f(unsigned short s) {
    return __uint_as_float((unsigned int)s << 16);
}
__device__ __forceinline__ unsigned int pack2bf(float a, float b) {
    return (unsigned int)f2bf(a) | ((unsigned int)f2bf(b) << 16);
}
__device__ __forceinline__ float bf2f_lo(unsigned int u) {
    return __uint_as_float(u << 16);
}
__device__ __forceinline__ float bf2f_hi(unsigned int u) {
    return __uint_as_float(u & 0xFFFF0000u);
}

// ---------------------------------------------------------------------------
// Setup: weight transpose+convert (z=0..8; z=0 also emits lo-plane for in_w)
// and batch lengths (z=9). Mode detection parallelized (was a 32-deep serial
// HBM-load chain per thread).
// ---------------------------------------------------------------------------
__global__ void k_setup(const float* __restrict__ in_w, const float* __restrict__ win_w,
                        const float* __restrict__ wout_w, const unsigned int* __restrict__ mask_w,
                        unsigned short* __restrict__ wt_in, unsigned short* __restrict__ wt_in_lo,
                        unsigned short* __restrict__ wt_win,
                        unsigned short* __restrict__ wt_wout, int* __restrict__ lengths) {
    int z = blockIdx.z;
    int tid = threadIdx.x;

    if (z == 9) {
        int b = blockIdx.y * 16 + blockIdx.x;
        if (b >= B_) return;
        __shared__ int smode;
        if (tid < 64) {                           // wave 0 only: parallel detect
            unsigned int w0 = mask_w[0];
            unsigned int vi = (tid < 32) ? mask_w[tid * 1024] : 0u;
            unsigned long long anyu8 = __ballot(vi > 1u);
            if (tid == 0) smode = (w0 == 0x3F800000u) ? 2 : (anyu8 ? 1 : 0);
        }
        __syncthreads();
        int mode = smode;
        int s = 0;
        if (mode == 0) {
            const int* m = (const int*)mask_w;
            for (int i = tid; i < S_; i += 256) s += (m[(size_t)b * S_ + i] != 0);
        } else if (mode == 2) {
            const float* m = (const float*)mask_w;
            for (int i = tid; i < S_; i += 256) s += (m[(size_t)b * S_ + i] != 0.0f);
        } else {
            const unsigned char* m = (const unsigned char*)mask_w;
            for (int i = tid; i < S_; i += 256) s += (m[(size_t)b * S_ + i] != 0);
        }
        __shared__ int sm[256];
        sm[tid] = s;
        __syncthreads();
        for (int off = 128; off > 0; off >>= 1) {
            if (tid < off) sm[tid] += sm[tid + off];
            __syncthreads();
        }
        if (tid == 0) lengths[b] = sm[0];
        return;
    }

    const float* src; unsigned short* dst; int N, Kd;
    if (z == 0)      { src = in_w;                                   dst = wt_in;                                   N = D_;     Kd = DIN_; }
    else if (z <= 4) { src = win_w  + (size_t)(z - 1) * D_ * 2 * D_; dst = wt_win  + (size_t)(z - 1) * 2 * D_ * D_; N = 2 * D_; Kd = D_; }
    else             { src = wout_w + (size_t)(z - 5) * D_ * D_;     dst = wt_wout + (size_t)(z - 5) * D_ * D_;     N = D_;     Kd = D_; }
    int bx = blockIdx.x * 32;
    int by = blockIdx.y * 32;
    if (bx >= N) return;
    __shared__ float tile[32][33];
    int tx = tid & 31, ty = tid >> 5;
#pragma unroll
    for (int i = 0; i < 32; i += 8)
        tile[ty + i][tx] = src[(size_t)(by + ty + i) * N + bx + tx];
    __syncthreads();
#pragma unroll
    for (int i = 0; i < 32; i += 8) {
        float f = tile[tx][ty + i];
        unsigned short h = f2bf(f);
        size_t idx = (size_t)(bx + ty + i) * Kd + by + tx;
        dst[idx] = h;
        if (z == 0) wt_in_lo[idx] = f2bf(f - bf2f(h));   // hi/lo split for in-proj
    }
}

// ---------------------------------------------------------------------------
// Fully fused network: compress + in-proj + 4 conv blocks + final LN.
// One block per (batch, 16-row segment); 32 rows computed (8 halo/side).
// 512 threads, 70KB LDS -> 2 blocks/CU. In-proj is split-precision bf16
// hi/lo (validated R5: absmax 0.0156). NEW this round: explicit cross-stage
// weight prefetch (Bf/Bn double-buffer, the proven baseline-k_blk pattern)
// -- hides win/wout L2 load latency under LN/act VALU phases. VGPR headroom:
// measured 64 of 128 allowed; prefetch spends ~32 of the idle half.
// ---------------------------------------------------------------------------
__global__ __launch_bounds__(512, 4) void k_fused(
    const float* __restrict__ x, const int* __restrict__ lengths,
    const unsigned short* __restrict__ wt_in, const unsigned short* __restrict__ wt_in_lo,
    const float* __restrict__ in_b,
    const float* __restrict__ ln_g, const float* __restrict__ ln_b,
    const float* __restrict__ dw_w, const float* __restrict__ dw_b,
    const unsigned short* __restrict__ wt_win, const float* __restrict__ win_b,
    const unsigned short* __restrict__ wt_wout, const float* __restrict__ wout_b,
    const float* __restrict__ fn_g, const float* __restrict__ fn_b,
    float* __restrict__ out0, float* __restrict__ out1)
{
    __shared__ unsigned short buf0[BR_][ASTR];   // 19.0 KB: x-lo plane / LN out / act
    __shared__ unsigned short buf1[CR_][ASTR];   // 16.9 KB: x-hi plane / conv out
    __shared__ float h_lds[CR_][HSTR];           // 33.8 KB: resident h (fp32)

    int tid = threadIdx.x;
    int w = tid >> 6, lane = tid & 63;
    int c16 = lane & 15, q = lane >> 4;
    int b = blockIdx.x >> 4, seg = blockIdx.x & (SEGS_ - 1);
    int t0 = seg * ORS_;
    // window row r in [0,32) corresponds to t = t0 - 8 + r

    unsigned short (*xlo)[ASTR] = (unsigned short (*)[ASTR])buf0;  // rows 0..31 alias

    int L = lengths[b];

    // ---- compress -> buf1 (hi) + buf0-alias (lo), bf16, 32 rows ----
    {
        int tq = tid & 63, rg = tid >> 6;
        int col = tq * 4;
        float Lf = (float)L;
        float hi = fmaxf(Lf - 1.0f, 0.0f);
        int L1 = max(L - 1, 0);
        const float* xb = x + (size_t)b * S_ * DIN_ + col;
#pragma unroll
        for (int e = 0; e < 4; ++e) {
            int row = rg + e * 8;
            int t = t0 - 8 + row;
            t = min(max(t, 0), T_ - 1);          // out-of-range halo rows: garbage ok, masked at LN
            float src = ((float)t + 0.5f) * (Lf * (1.0f / T_)) - 0.5f;
            src = fminf(fmaxf(src, 0.0f), hi);
            int i0 = (int)floorf(src);
            int i1 = min(i0 + 1, L1);
            float wf = src - (float)i0;
            float4 v0 = *(const float4*)&xb[(size_t)i0 * DIN_];
            float4 v1 = *(const float4*)&xb[(size_t)i1 * DIN_];
            float a0 = (1.0f - wf) * v0.x + wf * v1.x;
            float a1 = (1.0f - wf) * v0.y + wf * v1.y;
            float a2 = (1.0f - wf) * v0.z + wf * v1.z;
            float a3 = (1.0f - wf) * v0.w + wf * v1.w;
            unsigned short h0 = f2bf(a0), h1 = f2bf(a1), h2 = f2bf(a2), h3 = f2bf(a3);
            uint2 oh, ol;
            oh.x = (unsigned int)h0 | ((unsigned int)h1 << 16);
            oh.y = (unsigned int)h2 | ((unsigned int)h3 << 16);
            ol.x = (unsigned int)f2bf(a0 - bf2f(h0)) | ((unsigned int)f2bf(a1 - bf2f(h1)) << 16);
            ol.y = (unsigned int)f2bf(a2 - bf2f(h2)) | ((unsigned int)f2bf(a3 - bf2f(h3)) << 16);
            *(uint2*)&buf1[row][col] = oh;
            *(uint2*)&xlo[row][col] = ol;
        }
    }
    __syncthreads();

    // ---- in-proj GEMM (split precision): (Ahi+Alo)x(Whi+Wlo) ~ 3 MFMAs ----
#pragma unroll
    for (int nn = 0; nn < 2; ++nn) {
        int nt = w + nn * 8;
        const unsigned short* wph = wt_in    + (size_t)(nt * 16 + c16) * 256 + q * 8;
        const unsigned short* wpl = wt_in_lo + (size_t)(nt * 16 + c16) * 256 + q * 8;
        floatx4 acc[2] = {};
#pragma unroll
        for (int kk = 0; kk < 8; ++kk) {
            shortx8 bh = *(const shortx8*)(wph + kk * 32);
            shortx8 bl = *(const shortx8*)(wpl + kk * 32);
#pragma unroll
            for (int mt = 0; mt < 2; ++mt) {
                shortx8 ah = *(const shortx8*)&buf1[mt * 16 + c16][kk * 32 + q * 8];
                shortx8 al = *(const shortx8*)&xlo[mt * 16 + c16][kk * 32 + q * 8];
                acc[mt] = __builtin_amdgcn_mfma_f32_16x16x32_bf16(ah, bh, acc[mt], 0, 0, 0);
                acc[mt] = __builtin_amdgcn_mfma_f32_16x16x32_bf16(al, bh, acc[mt], 0, 0, 0);
                acc[mt] = __builtin_amdgcn_mfma_f32_16x16x32_bf16(ah, bl, acc[mt], 0, 0, 0);
            }
        }
        float obv = in_b[nt * 16 + c16];
#pragma unroll
        for (int mt = 0; mt < 2; ++mt)
#pragma unroll
            for (int r = 0; r < 4; ++r)
                h_lds[mt * 16 + q * 4 + r][nt * 16 + c16] = acc[mt][r] + obv;
    }
    __syncthreads();

    // zero the conv pad rows of buf0 (rows 0,1,34,35; x-lo plane is dead now;
    // disjoint from Stage A's rows 2..33, made visible by the A->B barrier)
    if (tid < 132) {
        ((unsigned int*)buf0[0])[tid] = 0u;
        ((unsigned int*)buf0[1])[tid] = 0u;
        ((unsigned int*)buf0[BR_ - 2])[tid] = 0u;
        ((unsigned int*)buf0[BR_ - 1])[tid] = 0u;
    }

    // ---- 4 conv blocks, h resident in LDS ----
    for (int li = 0; li < NB_; ++li) {
        const float* g_i = ln_g + li * D_;
        const float* b_i = ln_b + li * D_;
        const float* dww = dw_w + (size_t)li * D_ * K_;
        const float* dwb = dw_b + li * D_;
        const unsigned short* ww = wt_win + (size_t)li * 2 * D_ * D_;
        const float* wb = win_b + (size_t)li * 2 * D_;
        const unsigned short* ow = wt_wout + (size_t)li * D_ * D_;
        const float* obp = wout_b + li * D_;

        // prefetch win tile (w) for Stage C: issued here, latency hidden
        // under Stage A's LN compute + two barriers.
        shortx8 Bf[8];
        {
            const unsigned short* wp = ww + (size_t)(w * 16 + c16) * 256 + q * 8;
#pragma unroll
            for (int kk = 0; kk < 8; ++kk) Bf[kk] = *(const shortx8*)(wp + kk * 32);
        }

        // ---- Stage A: LN h_lds -> buf0 rows 2..33 (bf16), zero out-of-range t ----
        {
            int c4 = lane * 4;
            float4 g4 = *(const float4*)&g_i[c4];
            float4 b4 = *(const float4*)&b_i[c4];
#pragma unroll
            for (int it = 0; it < 4; ++it) {
                int r = w + it * 8;
                float4 v = *(const float4*)&h_lds[r][c4];
                float s  = v.x + v.y + v.z + v.w;
                float ss = v.x * v.x + v.y * v.y + v.z * v.z + v.w * v.w;
#pragma unroll
                for (int off = 1; off < 64; off <<= 1) {
                    s += __shfl_xor(s, off);
                    ss += __shfl_xor(ss, off);
                }
                float mu = s * (1.0f / D_);
                float rsig = rsqrtf(ss * (1.0f / D_) - mu * mu + EPS_);
                uint2 o;
                o.x = pack2bf((v.x - mu) * rsig * g4.x + b4.x,
                              (v.y - mu) * rsig * g4.y + b4.y);
                o.y = pack2bf((v.z - mu) * rsig * g4.z + b4.z,
                              (v.w - mu) * rsig * g4.w + b4.w);
                int t = t0 - 8 + r;
                if (t < 0 || t >= T_) { o.x = 0; o.y = 0; }   // zero-padded conv boundary
                *(uint2*)&buf0[r + 2][c4] = o;
            }
        }
        __syncthreads();

        // ---- Stage B: depthwise conv buf0 -> buf1 (32 rows) ----
        {
            int tq = tid & 63, rg = tid >> 6;
            int col = tq * 4;
            float4 wk[K_];
#pragma unroll
            for (int k = 0; k < K_; ++k) {
                wk[k].x = dww[(col + 0) * K_ + k];
                wk[k].y = dww[(col + 1) * K_ + k];
                wk[k].z = dww[(col + 2) * K_ + k];
                wk[k].w = dww[(col + 3) * K_ + k];
            }
            float4 cb4 = *(const float4*)&dwb[col];
#pragma unroll
            for (int e = 0; e < 4; ++e) {
                int rr = rg + e * 8;
                float4 acc = cb4;
#pragma unroll
                for (int k = 0; k < K_; ++k) {
                    uint2 u = *(const uint2*)&buf0[rr + k][col];
                    acc.x += bf2f_lo(u.x) * wk[k].x;
                    acc.y += bf2f_hi(u.x) * wk[k].y;
                    acc.z += bf2f_lo(u.y) * wk[k].z;
                    acc.w += bf2f_hi(u.y) * wk[k].w;
                }
                uint2 o;
                o.x = pack2bf(acc.x, acc.y);
                o.y = pack2bf(acc.z, acc.w);
                *(uint2*)&buf1[rr][col] = o;
            }
        }
        __syncthreads();

        // ---- Stage C: win GEMM (32x512) + fused act -> buf0 rows 2..33 ----
        // Pipelined weight prefetch: while computing with Bf (tile w+nn*8),
        // load Bn = next win tile, or wout tile w at nn=3. nn=0,1: gate tiles
        // kept in regs; nn=2,3: val tiles, act applied immediately.
        float gvreg[2][2][4];
#pragma unroll
        for (int nn = 0; nn < 4; ++nn) {
            shortx8 Bn[8];
            {
                const unsigned short* wp = (nn < 3)
                    ? ww + (size_t)((w + (nn + 1) * 8) * 16 + c16) * 256 + q * 8
                    : ow + (size_t)(w * 16 + c16) * 256 + q * 8;   // wout tile w
#pragma unroll
                for (int kk = 0; kk < 8; ++kk) Bn[kk] = *(const shortx8*)(wp + kk * 32);
            }
            floatx4 acc[2] = {};
#pragma unroll
            for (int kk = 0; kk < 8; ++kk)
#pragma unroll
                for (int mt = 0; mt < 2; ++mt) {
                    shortx8 a = *(const shortx8*)&buf1[mt * 16 + c16][kk * 32 + q * 8];
                    acc[mt] = __builtin_amdgcn_mfma_f32_16x16x32_bf16(a, Bf[kk], acc[mt], 0, 0, 0);
                }
            float bb = wb[(w + nn * 8) * 16 + c16];
            if (nn < 2) {
#pragma unroll
                for (int mt = 0; mt < 2; ++mt)
#pragma unroll
                    for (int r = 0; r < 4; ++r) gvreg[nn][mt][r] = acc[mt][r] + bb;
            } else {
                int pp = nn - 2;
                int colw = (w + pp * 8) * 16 + c16;
#pragma unroll
                for (int mt = 0; mt < 2; ++mt)
#pragma unroll
                    for (int r = 0; r < 4; ++r) {
                        float gate = gvreg[pp][mt][r];
                        float val  = acc[mt][r] + bb;
                        float sg = 1.0f / (1.0f + __expf(-gate));
                        float u = 1.5957691216f * (val + 0.044715f * val * val * val);
                        float ge = val / (1.0f + __expf(-u));
                        buf0[2 + mt * 16 + q * 4 + r][colw] = f2bf(sg * ge);
                    }
            }
#pragma unroll
            for (int kk = 0; kk < 8; ++kk) Bf[kk] = Bn[kk];
        }
        __syncthreads();

        // ---- Stage D: wout GEMM + residual (h_lds update, disjoint per thread) ----
        // Bf holds wout tile w (prefetched in C's nn=3); nn=0 prefetches
        // wout tile w+8 under its MFMAs.
#pragma unroll
        for (int nn = 0; nn < 2; ++nn) {
            int nt = w + nn * 8;
            shortx8 Bn[8];
            if (nn == 0) {
                const unsigned short* wp = ow + (size_t)((w + 8) * 16 + c16) * 256 + q * 8;
#pragma unroll
                for (int kk = 0; kk < 8; ++kk) Bn[kk] = *(const shortx8*)(wp + kk * 32);
            }
            floatx4 acc[2] = {};
#pragma unroll
            for (int kk = 0; kk < 8; ++kk)
#pragma unroll
                for (int mt = 0; mt < 2; ++mt) {
                    shortx8 a = *(const shortx8*)&buf0[2 + mt * 16 + c16][kk * 32 + q * 8];
                    acc[mt] = __builtin_amdgcn_mfma_f32_16x16x32_bf16(a, Bf[kk], acc[mt], 0, 0, 0);
                }
            float bb = obp[nt * 16 + c16];
#pragma unroll
            for (int mt = 0; mt < 2; ++mt)
#pragma unroll
                for (int r = 0; r < 4; ++r) {
                    int row = mt * 16 + q * 4 + r;
                    int col = nt * 16 + c16;
                    h_lds[row][col] = h_lds[row][col] + acc[mt][r] + bb;
                }
            if (nn == 0) {
#pragma unroll
                for (int kk = 0; kk < 8; ++kk) Bf[kk] = Bn[kk];
            }
        }
        __syncthreads();
    }

    // ---- final LN on owned rows (8..23) -> out0; comp_mask -> out1 ----
    {
        int c4 = lane * 4;
        float4 g4 = *(const float4*)&fn_g[c4];
        float4 b4 = *(const float4*)&fn_b[c4];
#pragma unroll
        for (int it = 0; it < 2; ++it) {
            int r = 8 + w + it * 8;
            float4 v = *(const float4*)&h_lds[r][c4];
            float s  = v.x + v.y + v.z + v.w;
            float ss = v.x * v.x + v.y * v.y + v.z * v.z + v.w * v.w;
#pragma unroll
            for (int off = 1; off < 64; off <<= 1) {
                s += __shfl_xor(s, off);
                ss += __shfl_xor(ss, off);
            }
            float mu = s * (1.0f / D_);
            float rsig = rsqrtf(ss * (1.0f / D_) - mu * mu + EPS_);
            float4 o;
            o.x = (v.x - mu) * rsig * g4.x + b4.x;
            o.y = (v.y - mu) * rsig * g4.y + b4.y;
            o.z = (v.z - mu) * rsig * g4.z + b4.z;
            o.w = (v.w - mu) * rsig * g4.w + b4.w;
            *(float4*)&out0[((size_t)b * T_ + t0 + r - 8) * D_ + c4] = o;
        }
        if (tid < ORS_) out1[(size_t)b * T_ + t0 + tid] = 1.0f;
    }
}

// ---------------------------------------------------------------------------
extern "C" void kernel_launch(void* const* d_in, const int* in_sizes, int n_in,
                              void* d_out, int out_size, void* d_ws, size_t ws_size,
                              hipStream_t stream) {
    const float* x      = (const float*)d_in[0];
    const unsigned int* mask_w = (const unsigned int*)d_in[1];
    const float* in_w   = (const float*)d_in[2];
    const float* in_b   = (const float*)d_in[3];
    const float* ln_g   = (const float*)d_in[4];
    const float* ln_b   = (const float*)d_in[5];
    const float* dw_w   = (const float*)d_in[6];
    const float* dw_b   = (const float*)d_in[7];
    const float* win_w  = (const float*)d_in[8];
    const float* win_b  = (const float*)d_in[9];
    const float* wout_w = (const float*)d_in[10];
    const float* wout_b = (const float*)d_in[11];
    const float* fn_g   = (const float*)d_in[12];
    const float* fn_b   = (const float*)d_in[13];

    char* w8 = (char*)d_ws;
    unsigned short* wt_in   = (unsigned short*)w8;                 // 128 KB
    unsigned short* wt_win  = wt_in  + (size_t)D_ * DIN_;          // 1 MB
    unsigned short* wt_wout = wt_win + (size_t)NB_ * 2 * D_ * D_;  // 512 KB
    int* lengths = (int*)(w8 + (2u << 20));                        // 128 B
    unsigned short* wt_in_lo = (unsigned short*)(w8 + (3u << 20)); // 128 KB

    float* out0 = (float*)d_out;
    float* out1 = out0 + (size_t)ROWS_ * D_;

    k_setup<<<dim3(16, 8, 10), 256, 0, stream>>>(in_w, win_w, wout_w, mask_w,
                                                 wt_in, wt_in_lo, wt_win, wt_wout, lengths);
    k_fused<<<B_ * SEGS_, 512, 0, stream>>>(x, lengths, wt_in, wt_in_lo, in_b,
                                            ln_g, ln_b, dw_w, dw_b,
                                            wt_win, win_b, wt_wout, wout_b,
                                            fn_g, fn_b, out0, out1);
}

// Round 7
// 319.458 us; speedup vs baseline: 1.0502x; 1.0502x over previous
//
#include <hip/hip_runtime.h>
#include <math.h>

#define B_    32
#define S_    4096
#define DIN_  256
#define D_    256
#define T_    256
#define NB_   4
#define K_    5
#define EPS_  1e-5f
#define ROWS_ (B_ * T_)   // 8192

#define ORS_  16          // owned rows per block
#define CR_   32          // computed rows = owned + 8 halo each side
#define BR_   36          // buf0 rows = CR_ + 2 conv-pad rows each side
#define SEGS_ 16          // T_/ORS_
#define ASTR  264         // bf16 row stride in shorts (528 B, 16B-aligned)
#define HSTR  264         // h_lds row stride in floats (1056 B, 16B-aligned)

typedef short  shortx8 __attribute__((ext_vector_type(8)));
typedef float  floatx4 __attribute__((ext_vector_type(4)));

__device__ __forceinline__ unsigned short f2bf(float f) {
    unsigned int u = __float_as_uint(f);
    u += 0x7FFFu + ((u >> 16) & 1u);
    return (unsigned short)(u >> 16);
}
__device__ __forceinline__ float bf2f(unsigned short s) {
    return __uint_as_float((unsigned int)s << 16);
}
__device__ __forceinline__ unsigned int pack2bf(float a, float b) {
    return (unsigned int)f2bf(a) | ((unsigned int)f2bf(b) << 16);
}
__device__ __forceinline__ float bf2f_lo(unsigned int u) {
    return __uint_as_float(u << 16);
}
__device__ __forceinline__ float bf2f_hi(unsigned int u) {
    return __uint_as_float(u & 0xFFFF0000u);
}

// ---------------------------------------------------------------------------
// Setup: weight transpose+convert (z=0..8; z=0 also emits lo-plane for in_w)
// and batch lengths (z=9).
// ---------------------------------------------------------------------------
__global__ void k_setup(const float* __restrict__ in_w, const float* __restrict__ win_w,
                        const float* __restrict__ wout_w, const unsigned int* __restrict__ mask_w,
                        unsigned short* __restrict__ wt_in, unsigned short* __restrict__ wt_in_lo,
                        unsigned short* __restrict__ wt_win,
                        unsigned short* __restrict__ wt_wout, int* __restrict__ lengths) {
    int z = blockIdx.z;
    int tid = threadIdx.x;

    if (z == 9) {
        int b = blockIdx.y * 16 + blockIdx.x;
        if (b >= B_) return;
        __shared__ int smode;
        if (tid < 64) {                           // wave 0 only: parallel detect
            unsigned int w0 = mask_w[0];
            unsigned int vi = (tid < 32) ? mask_w[tid * 1024] : 0u;
            unsigned long long anyu8 = __ballot(vi > 1u);
            if (tid == 0) smode = (w0 == 0x3F800000u) ? 2 : (anyu8 ? 1 : 0);
        }
        __syncthreads();
        int mode = smode;
        int s = 0;
        if (mode == 0) {
            const int* m = (const int*)mask_w;
            for (int i = tid; i < S_; i += 256) s += (m[(size_t)b * S_ + i] != 0);
        } else if (mode == 2) {
            const float* m = (const float*)mask_w;
            for (int i = tid; i < S_; i += 256) s += (m[(size_t)b * S_ + i] != 0.0f);
        } else {
            const unsigned char* m = (const unsigned char*)mask_w;
            for (int i = tid; i < S_; i += 256) s += (m[(size_t)b * S_ + i] != 0);
        }
        __shared__ int sm[256];
        sm[tid] = s;
        __syncthreads();
        for (int off = 128; off > 0; off >>= 1) {
            if (tid < off) sm[tid] += sm[tid + off];
            __syncthreads();
        }
        if (tid == 0) lengths[b] = sm[0];
        return;
    }

    const float* src; unsigned short* dst; int N, Kd;
    if (z == 0)      { src = in_w;                                   dst = wt_in;                                   N = D_;     Kd = DIN_; }
    else if (z <= 4) { src = win_w  + (size_t)(z - 1) * D_ * 2 * D_; dst = wt_win  + (size_t)(z - 1) * 2 * D_ * D_; N = 2 * D_; Kd = D_; }
    else             { src = wout_w + (size_t)(z - 5) * D_ * D_;     dst = wt_wout + (size_t)(z - 5) * D_ * D_;     N = D_;     Kd = D_; }
    int bx = blockIdx.x * 32;
    int by = blockIdx.y * 32;
    if (bx >= N) return;
    __shared__ float tile[32][33];
    int tx = tid & 31, ty = tid >> 5;
#pragma unroll
    for (int i = 0; i < 32; i += 8)
        tile[ty + i][tx] = src[(size_t)(by + ty + i) * N + bx + tx];
    __syncthreads();
#pragma unroll
    for (int i = 0; i < 32; i += 8) {
        float f = tile[tx][ty + i];
        unsigned short h = f2bf(f);
        size_t idx = (size_t)(bx + ty + i) * Kd + by + tx;
        dst[idx] = h;
        if (z == 0) wt_in_lo[idx] = f2bf(f - bf2f(h));   // hi/lo split for in-proj
    }
}

// ---------------------------------------------------------------------------
// Fully fused network: compress + in-proj + 4 conv blocks + final LN.
// One block per (batch, 16-row segment); 32 rows computed (8 halo/side).
// 512 threads, 70KB LDS -> 2 blocks/CU (LDS-limited). In-proj is
// split-precision bf16 hi/lo (validated R5: absmax 0.0156). Cross-stage
// weight prefetch (Bf/Bn double-buffer).
// R6 LESSON: __launch_bounds__(512,4) pinned VGPR at 64 (8 waves/SIMD cap,
// CUDA-style min-blocks interpretation) -> the prefetch SPILLED to scratch
// (+130MB HBM round-trip, +20us). (512,2) raises the cap to 128; occupancy
// stays LDS-limited at 2 blocks/CU, so this only un-spills the pipeline.
// ---------------------------------------------------------------------------
__global__ __launch_bounds__(512, 2) void k_fused(
    const float* __restrict__ x, const int* __restrict__ lengths,
    const unsigned short* __restrict__ wt_in, const unsigned short* __restrict__ wt_in_lo,
    const float* __restrict__ in_b,
    const float* __restrict__ ln_g, const float* __restrict__ ln_b,
    const float* __restrict__ dw_w, const float* __restrict__ dw_b,
    const unsigned short* __restrict__ wt_win, const float* __restrict__ win_b,
    const unsigned short* __restrict__ wt_wout, const float* __restrict__ wout_b,
    const float* __restrict__ fn_g, const float* __restrict__ fn_b,
    float* __restrict__ out0, float* __restrict__ out1)
{
    __shared__ unsigned short buf0[BR_][ASTR];   // 19.0 KB: x-lo plane / LN out / act
    __shared__ unsigned short buf1[CR_][ASTR];   // 16.9 KB: x-hi plane / conv out
    __shared__ float h_lds[CR_][HSTR];           // 33.8 KB: resident h (fp32)

    int tid = threadIdx.x;
    int w = tid >> 6, lane = tid & 63;
    int c16 = lane & 15, q = lane >> 4;
    int b = blockIdx.x >> 4, seg = blockIdx.x & (SEGS_ - 1);
    int t0 = seg * ORS_;
    // window row r in [0,32) corresponds to t = t0 - 8 + r

    unsigned short (*xlo)[ASTR] = (unsigned short (*)[ASTR])buf0;  // rows 0..31 alias

    int L = lengths[b];

    // ---- compress -> buf1 (hi) + buf0-alias (lo), bf16, 32 rows ----
    {
        int tq = tid & 63, rg = tid >> 6;
        int col = tq * 4;
        float Lf = (float)L;
        float hi = fmaxf(Lf - 1.0f, 0.0f);
        int L1 = max(L - 1, 0);
        const float* xb = x + (size_t)b * S_ * DIN_ + col;
#pragma unroll
        for (int e = 0; e < 4; ++e) {
            int row = rg + e * 8;
            int t = t0 - 8 + row;
            t = min(max(t, 0), T_ - 1);          // out-of-range halo rows: garbage ok, masked at LN
            float src = ((float)t + 0.5f) * (Lf * (1.0f / T_)) - 0.5f;
            src = fminf(fmaxf(src, 0.0f), hi);
            int i0 = (int)floorf(src);
            int i1 = min(i0 + 1, L1);
            float wf = src - (float)i0;
            float4 v0 = *(const float4*)&xb[(size_t)i0 * DIN_];
            float4 v1 = *(const float4*)&xb[(size_t)i1 * DIN_];
            float a0 = (1.0f - wf) * v0.x + wf * v1.x;
            float a1 = (1.0f - wf) * v0.y + wf * v1.y;
            float a2 = (1.0f - wf) * v0.z + wf * v1.z;
            float a3 = (1.0f - wf) * v0.w + wf * v1.w;
            unsigned short h0 = f2bf(a0), h1 = f2bf(a1), h2 = f2bf(a2), h3 = f2bf(a3);
            uint2 oh, ol;
            oh.x = (unsigned int)h0 | ((unsigned int)h1 << 16);
            oh.y = (unsigned int)h2 | ((unsigned int)h3 << 16);
            ol.x = (unsigned int)f2bf(a0 - bf2f(h0)) | ((unsigned int)f2bf(a1 - bf2f(h1)) << 16);
            ol.y = (unsigned int)f2bf(a2 - bf2f(h2)) | ((unsigned int)f2bf(a3 - bf2f(h3)) << 16);
            *(uint2*)&buf1[row][col] = oh;
            *(uint2*)&xlo[row][col] = ol;
        }
    }
    __syncthreads();

    // ---- in-proj GEMM (split precision): (Ahi+Alo)x(Whi+Wlo) ~ 3 MFMAs ----
#pragma unroll
    for (int nn = 0; nn < 2; ++nn) {
        int nt = w + nn * 8;
        const unsigned short* wph = wt_in    + (size_t)(nt * 16 + c16) * 256 + q * 8;
        const unsigned short* wpl = wt_in_lo + (size_t)(nt * 16 + c16) * 256 + q * 8;
        floatx4 acc[2] = {};
#pragma unroll
        for (int kk = 0; kk < 8; ++kk) {
            shortx8 bh = *(const shortx8*)(wph + kk * 32);
            shortx8 bl = *(const shortx8*)(wpl + kk * 32);
#pragma unroll
            for (int mt = 0; mt < 2; ++mt) {
                shortx8 ah = *(const shortx8*)&buf1[mt * 16 + c16][kk * 32 + q * 8];
                shortx8 al = *(const shortx8*)&xlo[mt * 16 + c16][kk * 32 + q * 8];
                acc[mt] = __builtin_amdgcn_mfma_f32_16x16x32_bf16(ah, bh, acc[mt], 0, 0, 0);
                acc[mt] = __builtin_amdgcn_mfma_f32_16x16x32_bf16(al, bh, acc[mt], 0, 0, 0);
                acc[mt] = __builtin_amdgcn_mfma_f32_16x16x32_bf16(ah, bl, acc[mt], 0, 0, 0);
            }
        }
        float obv = in_b[nt * 16 + c16];
#pragma unroll
        for (int mt = 0; mt < 2; ++mt)
#pragma unroll
            for (int r = 0; r < 4; ++r)
                h_lds[mt * 16 + q * 4 + r][nt * 16 + c16] = acc[mt][r] + obv;
    }
    __syncthreads();

    // zero the conv pad rows of buf0 (rows 0,1,34,35; x-lo plane is dead now;
    // disjoint from Stage A's rows 2..33, made visible by the A->B barrier)
    if (tid < 132) {
        ((unsigned int*)buf0[0])[tid] = 0u;
        ((unsigned int*)buf0[1])[tid] = 0u;
        ((unsigned int*)buf0[BR_ - 2])[tid] = 0u;
        ((unsigned int*)buf0[BR_ - 1])[tid] = 0u;
    }

    // ---- 4 conv blocks, h resident in LDS ----
    for (int li = 0; li < NB_; ++li) {
        const float* g_i = ln_g + li * D_;
        const float* b_i = ln_b + li * D_;
        const float* dww = dw_w + (size_t)li * D_ * K_;
        const float* dwb = dw_b + li * D_;
        const unsigned short* ww = wt_win + (size_t)li * 2 * D_ * D_;
        const float* wb = win_b + (size_t)li * 2 * D_;
        const unsigned short* ow = wt_wout + (size_t)li * D_ * D_;
        const float* obp = wout_b + li * D_;

        // prefetch win tile (w) for Stage C: issued here, latency hidden
        // under Stage A's LN compute + two barriers.
        shortx8 Bf[8];
        {
            const unsigned short* wp = ww + (size_t)(w * 16 + c16) * 256 + q * 8;
#pragma unroll
            for (int kk = 0; kk < 8; ++kk) Bf[kk] = *(const shortx8*)(wp + kk * 32);
        }

        // ---- Stage A: LN h_lds -> buf0 rows 2..33 (bf16), zero out-of-range t ----
        {
            int c4 = lane * 4;
            float4 g4 = *(const float4*)&g_i[c4];
            float4 b4 = *(const float4*)&b_i[c4];
#pragma unroll
            for (int it = 0; it < 4; ++it) {
                int r = w + it * 8;
                float4 v = *(const float4*)&h_lds[r][c4];
                float s  = v.x + v.y + v.z + v.w;
                float ss = v.x * v.x + v.y * v.y + v.z * v.z + v.w * v.w;
#pragma unroll
                for (int off = 1; off < 64; off <<= 1) {
                    s += __shfl_xor(s, off);
                    ss += __shfl_xor(ss, off);
                }
                float mu = s * (1.0f / D_);
                float rsig = rsqrtf(ss * (1.0f / D_) - mu * mu + EPS_);
                uint2 o;
                o.x = pack2bf((v.x - mu) * rsig * g4.x + b4.x,
                              (v.y - mu) * rsig * g4.y + b4.y);
                o.y = pack2bf((v.z - mu) * rsig * g4.z + b4.z,
                              (v.w - mu) * rsig * g4.w + b4.w);
                int t = t0 - 8 + r;
                if (t < 0 || t >= T_) { o.x = 0; o.y = 0; }   // zero-padded conv boundary
                *(uint2*)&buf0[r + 2][c4] = o;
            }
        }
        __syncthreads();

        // ---- Stage B: depthwise conv buf0 -> buf1 (32 rows) ----
        {
            int tq = tid & 63, rg = tid >> 6;
            int col = tq * 4;
            float4 wk[K_];
#pragma unroll
            for (int k = 0; k < K_; ++k) {
                wk[k].x = dww[(col + 0) * K_ + k];
                wk[k].y = dww[(col + 1) * K_ + k];
                wk[k].z = dww[(col + 2) * K_ + k];
                wk[k].w = dww[(col + 3) * K_ + k];
            }
            float4 cb4 = *(const float4*)&dwb[col];
#pragma unroll
            for (int e = 0; e < 4; ++e) {
                int rr = rg + e * 8;
                float4 acc = cb4;
#pragma unroll
                for (int k = 0; k < K_; ++k) {
                    uint2 u = *(const uint2*)&buf0[rr + k][col];
                    acc.x += bf2f_lo(u.x) * wk[k].x;
                    acc.y += bf2f_hi(u.x) * wk[k].y;
                    acc.z += bf2f_lo(u.y) * wk[k].z;
                    acc.w += bf2f_hi(u.y) * wk[k].w;
                }
                uint2 o;
                o.x = pack2bf(acc.x, acc.y);
                o.y = pack2bf(acc.z, acc.w);
                *(uint2*)&buf1[rr][col] = o;
            }
        }
        __syncthreads();

        // ---- Stage C: win GEMM (32x512) + fused act -> buf0 rows 2..33 ----
        // Pipelined weight prefetch: while computing with Bf (tile w+nn*8),
        // load Bn = next win tile, or wout tile w at nn=3. nn=0,1: gate tiles
        // kept in regs; nn=2,3: val tiles, act applied immediately.
        float gvreg[2][2][4];
#pragma unroll
        for (int nn = 0; nn < 4; ++nn) {
            shortx8 Bn[8];
            {
                const unsigned short* wp = (nn < 3)
                    ? ww + (size_t)((w + (nn + 1) * 8) * 16 + c16) * 256 + q * 8
                    : ow + (size_t)(w * 16 + c16) * 256 + q * 8;   // wout tile w
#pragma unroll
                for (int kk = 0; kk < 8; ++kk) Bn[kk] = *(const shortx8*)(wp + kk * 32);
            }
            floatx4 acc[2] = {};
#pragma unroll
            for (int kk = 0; kk < 8; ++kk)
#pragma unroll
                for (int mt = 0; mt < 2; ++mt) {
                    shortx8 a = *(const shortx8*)&buf1[mt * 16 + c16][kk * 32 + q * 8];
                    acc[mt] = __builtin_amdgcn_mfma_f32_16x16x32_bf16(a, Bf[kk], acc[mt], 0, 0, 0);
                }
            float bb = wb[(w + nn * 8) * 16 + c16];
            if (nn < 2) {
#pragma unroll
                for (int mt = 0; mt < 2; ++mt)
#pragma unroll
                    for (int r = 0; r < 4; ++r) gvreg[nn][mt][r] = acc[mt][r] + bb;
            } else {
                int pp = nn - 2;
                int colw = (w + pp * 8) * 16 + c16;
#pragma unroll
                for (int mt = 0; mt < 2; ++mt)
#pragma unroll
                    for (int r = 0; r < 4; ++r) {
                        float gate = gvreg[pp][mt][r];
                        float val  = acc[mt][r] + bb;
                        float sg = 1.0f / (1.0f + __expf(-gate));
                        float u = 1.5957691216f * (val + 0.044715f * val * val * val);
                        float ge = val / (1.0f + __expf(-u));
                        buf0[2 + mt * 16 + q * 4 + r][colw] = f2bf(sg * ge);
                    }
            }
#pragma unroll
            for (int kk = 0; kk < 8; ++kk) Bf[kk] = Bn[kk];
        }
        __syncthreads();

        // ---- Stage D: wout GEMM + residual (h_lds update, disjoint per thread) ----
        // Bf holds wout tile w (prefetched in C's nn=3); nn=0 prefetches
        // wout tile w+8 under its MFMAs.
#pragma unroll
        for (int nn = 0; nn < 2; ++nn) {
            int nt = w + nn * 8;
            shortx8 Bn[8];
            if (nn == 0) {
                const unsigned short* wp = ow + (size_t)((w + 8) * 16 + c16) * 256 + q * 8;
#pragma unroll
                for (int kk = 0; kk < 8; ++kk) Bn[kk] = *(const shortx8*)(wp + kk * 32);
            }
            floatx4 acc[2] = {};
#pragma unroll
            for (int kk = 0; kk < 8; ++kk)
#pragma unroll
                for (int mt = 0; mt < 2; ++mt) {
                    shortx8 a = *(const shortx8*)&buf0[2 + mt * 16 + c16][kk * 32 + q * 8];
                    acc[mt] = __builtin_amdgcn_mfma_f32_16x16x32_bf16(a, Bf[kk], acc[mt], 0, 0, 0);
                }
            float bb = obp[nt * 16 + c16];
#pragma unroll
            for (int mt = 0; mt < 2; ++mt)
#pragma unroll
                for (int r = 0; r < 4; ++r) {
                    int row = mt * 16 + q * 4 + r;
                    int col = nt * 16 + c16;
                    h_lds[row][col] = h_lds[row][col] + acc[mt][r] + bb;
                }
            if (nn == 0) {
#pragma unroll
                for (int kk = 0; kk < 8; ++kk) Bf[kk] = Bn[kk];
            }
        }
        __syncthreads();
    }

    // ---- final LN on owned rows (8..23) -> out0; comp_mask -> out1 ----
    {
        int c4 = lane * 4;
        float4 g4 = *(const float4*)&fn_g[c4];
        float4 b4 = *(const float4*)&fn_b[c4];
#pragma unroll
        for (int it = 0; it < 2; ++it) {
            int r = 8 + w + it * 8;
            float4 v = *(const float4*)&h_lds[r][c4];
            float s  = v.x + v.y + v.z + v.w;
            float ss = v.x * v.x + v.y * v.y + v.z * v.z + v.w * v.w;
#pragma unroll
            for (int off = 1; off < 64; off <<= 1) {
                s += __shfl_xor(s, off);
                ss += __shfl_xor(ss, off);
            }
            float mu = s * (1.0f / D_);
            float rsig = rsqrtf(ss * (1.0f / D_) - mu * mu + EPS_);
            float4 o;
            o.x = (v.x - mu) * rsig * g4.x + b4.x;
            o.y = (v.y - mu) * rsig * g4.y + b4.y;
            o.z = (v.z - mu) * rsig * g4.z + b4.z;
            o.w = (v.w - mu) * rsig * g4.w + b4.w;
            *(float4*)&out0[((size_t)b * T_ + t0 + r - 8) * D_ + c4] = o;
        }
        if (tid < ORS_) out1[(size_t)b * T_ + t0 + tid] = 1.0f;
    }
}

// ---------------------------------------------------------------------------
extern "C" void kernel_launch(void* const* d_in, const int* in_sizes, int n_in,
                              void* d_out, int out_size, void* d_ws, size_t ws_size,
                              hipStream_t stream) {
    const float* x      = (const float*)d_in[0];
    const unsigned int* mask_w = (const unsigned int*)d_in[1];
    const float* in_w   = (const float*)d_in[2];
    const float* in_b   = (const float*)d_in[3];
    const float* ln_g   = (const float*)d_in[4];
    const float* ln_b   = (const float*)d_in[5];
    const float* dw_w   = (const float*)d_in[6];
    const float* dw_b   = (const float*)d_in[7];
    const float* win_w  = (const float*)d_in[8];
    const float* win_b  = (const float*)d_in[9];
    const float* wout_w = (const float*)d_in[10];
    const float* wout_b = (const float*)d_in[11];
    const float* fn_g   = (const float*)d_in[12];
    const float* fn_b   = (const float*)d_in[13];

    char* w8 = (char*)d_ws;
    unsigned short* wt_in   = (unsigned short*)w8;                 // 128 KB
    unsigned short* wt_win  = wt_in  + (size_t)D_ * DIN_;          // 1 MB
    unsigned short* wt_wout = wt_win + (size_t)NB_ * 2 * D_ * D_;  // 512 KB
    int* lengths = (int*)(w8 + (2u << 20));                        // 128 B
    unsigned short* wt_in_lo = (unsigned short*)(w8 + (3u << 20)); // 128 KB

    float* out0 = (float*)d_out;
    float* out1 = out0 + (size_t)ROWS_ * D_;

    k_setup<<<dim3(16, 8, 10), 256, 0, stream>>>(in_w, win_w, wout_w, mask_w,
                                                 wt_in, wt_in_lo, wt_win, wt_wout, lengths);
    k_fused<<<B_ * SEGS_, 512, 0, stream>>>(x, lengths, wt_in, wt_in_lo, in_b,
                                            ln_g, ln_b, dw_w, dw_b,
                                            wt_win, win_b, wt_wout, wout_b,
                                            fn_g, fn_b, out0, out1);
}

// Round 8
// 315.064 us; speedup vs baseline: 1.0648x; 1.0139x over previous
//
#include <hip/hip_runtime.h>
#include <math.h>

#define B_    32
#define S_    4096
#define DIN_  256
#define D_    256
#define T_    256
#define NB_   4
#define K_    5
#define EPS_  1e-5f
#define ROWS_ (B_ * T_)   // 8192

#define ORS_  16          // owned rows per block
#define CR_   32          // computed rows = owned + 8 halo each side
#define BR_   36          // buf0 rows = CR_ + 2 conv-pad rows each side
#define SEGS_ 16          // T_/ORS_
#define ASTR  264         // bf16 row stride in shorts (528 B, 16B-aligned)
#define HSTR  264         // h_lds row stride in floats (1056 B, 16B-aligned)

typedef short  shortx8  __attribute__((ext_vector_type(8)));
typedef float  floatx4  __attribute__((ext_vector_type(4)));
typedef float  floatx16 __attribute__((ext_vector_type(16)));

__device__ __forceinline__ unsigned short f2bf(float f) {
    unsigned int u = __float_as_uint(f);
    u += 0x7FFFu + ((u >> 16) & 1u);
    return (unsigned short)(u >> 16);
}
__device__ __forceinline__ float bf2f(unsigned short s) {
    return __uint_as_float((unsigned int)s << 16);
}
__device__ __forceinline__ unsigned int pack2bf(float a, float b) {
    return (unsigned int)f2bf(a) | ((unsigned int)f2bf(b) << 16);
}
__device__ __forceinline__ float bf2f_lo(unsigned int u) {
    return __uint_as_float(u << 16);
}
__device__ __forceinline__ float bf2f_hi(unsigned int u) {
    return __uint_as_float(u & 0xFFFF0000u);
}

// ---------------------------------------------------------------------------
// Setup: weight transpose+convert (z=0..8; z=0 also emits lo-plane for in_w)
// and batch lengths (z=9).
// ---------------------------------------------------------------------------
__global__ void k_setup(const float* __restrict__ in_w, const float* __restrict__ win_w,
                        const float* __restrict__ wout_w, const unsigned int* __restrict__ mask_w,
                        unsigned short* __restrict__ wt_in, unsigned short* __restrict__ wt_in_lo,
                        unsigned short* __restrict__ wt_win,
                        unsigned short* __restrict__ wt_wout, int* __restrict__ lengths) {
    int z = blockIdx.z;
    int tid = threadIdx.x;

    if (z == 9) {
        int b = blockIdx.y * 16 + blockIdx.x;
        if (b >= B_) return;
        __shared__ int smode;
        if (tid < 64) {                           // wave 0 only: parallel detect
            unsigned int w0 = mask_w[0];
            unsigned int vi = (tid < 32) ? mask_w[tid * 1024] : 0u;
            unsigned long long anyu8 = __ballot(vi > 1u);
            if (tid == 0) smode = (w0 == 0x3F800000u) ? 2 : (anyu8 ? 1 : 0);
        }
        __syncthreads();
        int mode = smode;
        int s = 0;
        if (mode == 0) {
            const int* m = (const int*)mask_w;
            for (int i = tid; i < S_; i += 256) s += (m[(size_t)b * S_ + i] != 0);
        } else if (mode == 2) {
            const float* m = (const float*)mask_w;
            for (int i = tid; i < S_; i += 256) s += (m[(size_t)b * S_ + i] != 0.0f);
        } else {
            const unsigned char* m = (const unsigned char*)mask_w;
            for (int i = tid; i < S_; i += 256) s += (m[(size_t)b * S_ + i] != 0);
        }
        __shared__ int sm[256];
        sm[tid] = s;
        __syncthreads();
        for (int off = 128; off > 0; off >>= 1) {
            if (tid < off) sm[tid] += sm[tid + off];
            __syncthreads();
        }
        if (tid == 0) lengths[b] = sm[0];
        return;
    }

    const float* src; unsigned short* dst; int N, Kd;
    if (z == 0)      { src = in_w;                                   dst = wt_in;                                   N = D_;     Kd = DIN_; }
    else if (z <= 4) { src = win_w  + (size_t)(z - 1) * D_ * 2 * D_; dst = wt_win  + (size_t)(z - 1) * 2 * D_ * D_; N = 2 * D_; Kd = D_; }
    else             { src = wout_w + (size_t)(z - 5) * D_ * D_;     dst = wt_wout + (size_t)(z - 5) * D_ * D_;     N = D_;     Kd = D_; }
    int bx = blockIdx.x * 32;
    int by = blockIdx.y * 32;
    if (bx >= N) return;
    __shared__ float tile[32][33];
    int tx = tid & 31, ty = tid >> 5;
#pragma unroll
    for (int i = 0; i < 32; i += 8)
        tile[ty + i][tx] = src[(size_t)(by + ty + i) * N + bx + tx];
    __syncthreads();
#pragma unroll
    for (int i = 0; i < 32; i += 8) {
        float f = tile[tx][ty + i];
        unsigned short h = f2bf(f);
        size_t idx = (size_t)(bx + ty + i) * Kd + by + tx;
        dst[idx] = h;
        if (z == 0) wt_in_lo[idx] = f2bf(f - bf2f(h));   // hi/lo split for in-proj
    }
}

// ---------------------------------------------------------------------------
// Fully fused network: compress + in-proj + 4 conv blocks + final LN.
// One block per (batch, 16-row segment); 32 rows computed (8 halo/side).
// 512 threads, 70KB LDS. In-proj is split-precision bf16 hi/lo (validated
// R5: absmax 0.0156).
// R7 LESSON: perf invariant to occupancy (8 vs 16 waves/CU) and registers
// -> bottleneck is the shared per-CU LDS pipe (GEMM A-fragment re-reads
// dominate DS issue). THIS ROUND: Stages C and D use 32x32x16 MFMA; one
// A b128-read per K-step is shared across both output tiles -> C: 64->16,
// D: 32->16 ds_reads/wave/layer. B streams from L2 inline (no reg dbuf).
// C/D reg->(row,col): col=lane&31, row=(reg&3)+8*(reg>>2)+4*(lane>>5)
// (HW-verified m74/m101); A frag: lane -> row=lane&31, k=8*(lane>>5)+[0..7].
// ---------------------------------------------------------------------------
__global__ __launch_bounds__(512, 2) void k_fused(
    const float* __restrict__ x, const int* __restrict__ lengths,
    const unsigned short* __restrict__ wt_in, const unsigned short* __restrict__ wt_in_lo,
    const float* __restrict__ in_b,
    const float* __restrict__ ln_g, const float* __restrict__ ln_b,
    const float* __restrict__ dw_w, const float* __restrict__ dw_b,
    const unsigned short* __restrict__ wt_win, const float* __restrict__ win_b,
    const unsigned short* __restrict__ wt_wout, const float* __restrict__ wout_b,
    const float* __restrict__ fn_g, const float* __restrict__ fn_b,
    float* __restrict__ out0, float* __restrict__ out1)
{
    __shared__ unsigned short buf0[BR_][ASTR];   // 19.0 KB: x-lo plane / LN out / act
    __shared__ unsigned short buf1[CR_][ASTR];   // 16.9 KB: x-hi plane / conv out
    __shared__ float h_lds[CR_][HSTR];           // 33.8 KB: resident h (fp32)

    int tid = threadIdx.x;
    int w = tid >> 6, lane = tid & 63;
    int c16 = lane & 15, q = lane >> 4;
    int l31 = lane & 31, lh = lane >> 5;         // 32x32 fragment coords
    int b = blockIdx.x >> 4, seg = blockIdx.x & (SEGS_ - 1);
    int t0 = seg * ORS_;
    // window row r in [0,32) corresponds to t = t0 - 8 + r

    unsigned short (*xlo)[ASTR] = (unsigned short (*)[ASTR])buf0;  // rows 0..31 alias

    int L = lengths[b];

    // ---- compress -> buf1 (hi) + buf0-alias (lo), bf16, 32 rows ----
    {
        int tq = tid & 63, rg = tid >> 6;
        int col = tq * 4;
        float Lf = (float)L;
        float hi = fmaxf(Lf - 1.0f, 0.0f);
        int L1 = max(L - 1, 0);
        const float* xb = x + (size_t)b * S_ * DIN_ + col;
#pragma unroll
        for (int e = 0; e < 4; ++e) {
            int row = rg + e * 8;
            int t = t0 - 8 + row;
            t = min(max(t, 0), T_ - 1);          // out-of-range halo rows: garbage ok, masked at LN
            float src = ((float)t + 0.5f) * (Lf * (1.0f / T_)) - 0.5f;
            src = fminf(fmaxf(src, 0.0f), hi);
            int i0 = (int)floorf(src);
            int i1 = min(i0 + 1, L1);
            float wf = src - (float)i0;
            float4 v0 = *(const float4*)&xb[(size_t)i0 * DIN_];
            float4 v1 = *(const float4*)&xb[(size_t)i1 * DIN_];
            float a0 = (1.0f - wf) * v0.x + wf * v1.x;
            float a1 = (1.0f - wf) * v0.y + wf * v1.y;
            float a2 = (1.0f - wf) * v0.z + wf * v1.z;
            float a3 = (1.0f - wf) * v0.w + wf * v1.w;
            unsigned short h0 = f2bf(a0), h1 = f2bf(a1), h2 = f2bf(a2), h3 = f2bf(a3);
            uint2 oh, ol;
            oh.x = (unsigned int)h0 | ((unsigned int)h1 << 16);
            oh.y = (unsigned int)h2 | ((unsigned int)h3 << 16);
            ol.x = (unsigned int)f2bf(a0 - bf2f(h0)) | ((unsigned int)f2bf(a1 - bf2f(h1)) << 16);
            ol.y = (unsigned int)f2bf(a2 - bf2f(h2)) | ((unsigned int)f2bf(a3 - bf2f(h3)) << 16);
            *(uint2*)&buf1[row][col] = oh;
            *(uint2*)&xlo[row][col] = ol;
        }
    }
    __syncthreads();

    // ---- in-proj GEMM (split precision): (Ahi+Alo)x(Whi+Wlo) ~ 3 MFMAs ----
#pragma unroll
    for (int nn = 0; nn < 2; ++nn) {
        int nt = w + nn * 8;
        const unsigned short* wph = wt_in    + (size_t)(nt * 16 + c16) * 256 + q * 8;
        const unsigned short* wpl = wt_in_lo + (size_t)(nt * 16 + c16) * 256 + q * 8;
        floatx4 acc[2] = {};
#pragma unroll
        for (int kk = 0; kk < 8; ++kk) {
            shortx8 bh = *(const shortx8*)(wph + kk * 32);
            shortx8 bl = *(const shortx8*)(wpl + kk * 32);
#pragma unroll
            for (int mt = 0; mt < 2; ++mt) {
                shortx8 ah = *(const shortx8*)&buf1[mt * 16 + c16][kk * 32 + q * 8];
                shortx8 al = *(const shortx8*)&xlo[mt * 16 + c16][kk * 32 + q * 8];
                acc[mt] = __builtin_amdgcn_mfma_f32_16x16x32_bf16(ah, bh, acc[mt], 0, 0, 0);
                acc[mt] = __builtin_amdgcn_mfma_f32_16x16x32_bf16(al, bh, acc[mt], 0, 0, 0);
                acc[mt] = __builtin_amdgcn_mfma_f32_16x16x32_bf16(ah, bl, acc[mt], 0, 0, 0);
            }
        }
        float obv = in_b[nt * 16 + c16];
#pragma unroll
        for (int mt = 0; mt < 2; ++mt)
#pragma unroll
            for (int r = 0; r < 4; ++r)
                h_lds[mt * 16 + q * 4 + r][nt * 16 + c16] = acc[mt][r] + obv;
    }
    __syncthreads();

    // zero the conv pad rows of buf0 (rows 0,1,34,35; x-lo plane is dead now;
    // disjoint from Stage A's rows 2..33, made visible by the A->B barrier)
    if (tid < 132) {
        ((unsigned int*)buf0[0])[tid] = 0u;
        ((unsigned int*)buf0[1])[tid] = 0u;
        ((unsigned int*)buf0[BR_ - 2])[tid] = 0u;
        ((unsigned int*)buf0[BR_ - 1])[tid] = 0u;
    }

    // ---- 4 conv blocks, h resident in LDS ----
    for (int li = 0; li < NB_; ++li) {
        const float* g_i = ln_g + li * D_;
        const float* b_i = ln_b + li * D_;
        const float* dww = dw_w + (size_t)li * D_ * K_;
        const float* dwb = dw_b + li * D_;
        const unsigned short* ww = wt_win + (size_t)li * 2 * D_ * D_;
        const float* wb = win_b + (size_t)li * 2 * D_;
        const unsigned short* ow = wt_wout + (size_t)li * D_ * D_;
        const float* obp = wout_b + li * D_;

        // ---- Stage A: LN h_lds -> buf0 rows 2..33 (bf16), zero out-of-range t ----
        {
            int c4 = lane * 4;
            float4 g4 = *(const float4*)&g_i[c4];
            float4 b4 = *(const float4*)&b_i[c4];
#pragma unroll
            for (int it = 0; it < 4; ++it) {
                int r = w + it * 8;
                float4 v = *(const float4*)&h_lds[r][c4];
                float s  = v.x + v.y + v.z + v.w;
                float ss = v.x * v.x + v.y * v.y + v.z * v.z + v.w * v.w;
#pragma unroll
                for (int off = 1; off < 64; off <<= 1) {
                    s += __shfl_xor(s, off);
                    ss += __shfl_xor(ss, off);
                }
                float mu = s * (1.0f / D_);
                float rsig = rsqrtf(ss * (1.0f / D_) - mu * mu + EPS_);
                uint2 o;
                o.x = pack2bf((v.x - mu) * rsig * g4.x + b4.x,
                              (v.y - mu) * rsig * g4.y + b4.y);
                o.y = pack2bf((v.z - mu) * rsig * g4.z + b4.z,
                              (v.w - mu) * rsig * g4.w + b4.w);
                int t = t0 - 8 + r;
                if (t < 0 || t >= T_) { o.x = 0; o.y = 0; }   // zero-padded conv boundary
                *(uint2*)&buf0[r + 2][c4] = o;
            }
        }
        __syncthreads();

        // ---- Stage B: depthwise conv buf0 -> buf1 (32 rows) ----
        {
            int tq = tid & 63, rg = tid >> 6;
            int col = tq * 4;
            float4 wk[K_];
#pragma unroll
            for (int k = 0; k < K_; ++k) {
                wk[k].x = dww[(col + 0) * K_ + k];
                wk[k].y = dww[(col + 1) * K_ + k];
                wk[k].z = dww[(col + 2) * K_ + k];
                wk[k].w = dww[(col + 3) * K_ + k];
            }
            float4 cb4 = *(const float4*)&dwb[col];
#pragma unroll
            for (int e = 0; e < 4; ++e) {
                int rr = rg + e * 8;
                float4 acc = cb4;
#pragma unroll
                for (int k = 0; k < K_; ++k) {
                    uint2 u = *(const uint2*)&buf0[rr + k][col];
                    acc.x += bf2f_lo(u.x) * wk[k].x;
                    acc.y += bf2f_hi(u.x) * wk[k].y;
                    acc.z += bf2f_lo(u.y) * wk[k].z;
                    acc.w += bf2f_hi(u.y) * wk[k].w;
                }
                uint2 o;
                o.x = pack2bf(acc.x, acc.y);
                o.y = pack2bf(acc.z, acc.w);
                *(uint2*)&buf1[rr][col] = o;
            }
        }
        __syncthreads();

        // ---- Stage C: win GEMM (32x512) via 32x32x16 MFMA + fused act ----
        // Wave w owns gate cols [w*32,w*32+32) and val cols [256+w*32, ...).
        // One A-read per K-step feeds BOTH tiles (2 independent MFMA chains).
        {
            floatx16 accG = {}, accV = {};
            const unsigned short* wgp = ww + (size_t)(w * 32 + l31) * 256 + lh * 8;
            const unsigned short* wvp = ww + (size_t)(256 + w * 32 + l31) * 256 + lh * 8;
#pragma unroll
            for (int kk = 0; kk < 16; ++kk) {
                shortx8 a  = *(const shortx8*)&buf1[l31][kk * 16 + lh * 8];
                shortx8 bg = *(const shortx8*)(wgp + kk * 16);
                shortx8 bv = *(const shortx8*)(wvp + kk * 16);
                accG = __builtin_amdgcn_mfma_f32_32x32x16_bf16(a, bg, accG, 0, 0, 0);
                accV = __builtin_amdgcn_mfma_f32_32x32x16_bf16(a, bv, accV, 0, 0, 0);
            }
            float bg0 = wb[w * 32 + l31];
            float bv0 = wb[256 + w * 32 + l31];
#pragma unroll
            for (int r = 0; r < 16; ++r) {
                int row = (r & 3) + 8 * (r >> 2) + 4 * lh;
                float gate = accG[r] + bg0;
                float val  = accV[r] + bv0;
                float sg = 1.0f / (1.0f + __expf(-gate));
                float u = 1.5957691216f * (val + 0.044715f * val * val * val);
                float ge = val / (1.0f + __expf(-u));
                buf0[2 + row][w * 32 + l31] = f2bf(sg * ge);
            }
        }
        __syncthreads();

        // ---- Stage D: wout GEMM (32x256) via 32x32x16 + residual ----
        {
            floatx16 acc = {};
            const unsigned short* wop = ow + (size_t)(w * 32 + l31) * 256 + lh * 8;
#pragma unroll
            for (int kk = 0; kk < 16; ++kk) {
                shortx8 a  = *(const shortx8*)&buf0[2 + l31][kk * 16 + lh * 8];
                shortx8 bo = *(const shortx8*)(wop + kk * 16);
                acc = __builtin_amdgcn_mfma_f32_32x32x16_bf16(a, bo, acc, 0, 0, 0);
            }
            float bb = obp[w * 32 + l31];
#pragma unroll
            for (int r = 0; r < 16; ++r) {
                int row = (r & 3) + 8 * (r >> 2) + 4 * lh;
                int col = w * 32 + l31;
                h_lds[row][col] = h_lds[row][col] + acc[r] + bb;
            }
        }
        __syncthreads();
    }

    // ---- final LN on owned rows (8..23) -> out0; comp_mask -> out1 ----
    {
        int c4 = lane * 4;
        float4 g4 = *(const float4*)&fn_g[c4];
        float4 b4 = *(const float4*)&fn_b[c4];
#pragma unroll
        for (int it = 0; it < 2; ++it) {
            int r = 8 + w + it * 8;
            float4 v = *(const float4*)&h_lds[r][c4];
            float s  = v.x + v.y + v.z + v.w;
            float ss = v.x * v.x + v.y * v.y + v.z * v.z + v.w * v.w;
#pragma unroll
            for (int off = 1; off < 64; off <<= 1) {
                s += __shfl_xor(s, off);
                ss += __shfl_xor(ss, off);
            }
            float mu = s * (1.0f / D_);
            float rsig = rsqrtf(ss * (1.0f / D_) - mu * mu + EPS_);
            float4 o;
            o.x = (v.x - mu) * rsig * g4.x + b4.x;
            o.y = (v.y - mu) * rsig * g4.y + b4.y;
            o.z = (v.z - mu) * rsig * g4.z + b4.z;
            o.w = (v.w - mu) * rsig * g4.w + b4.w;
            *(float4*)&out0[((size_t)b * T_ + t0 + r - 8) * D_ + c4] = o;
        }
        if (tid < ORS_) out1[(size_t)b * T_ + t0 + tid] = 1.0f;
    }
}

// ---------------------------------------------------------------------------
extern "C" void kernel_launch(void* const* d_in, const int* in_sizes, int n_in,
                              void* d_out, int out_size, void* d_ws, size_t ws_size,
                              hipStream_t stream) {
    const float* x      = (const float*)d_in[0];
    const unsigned int* mask_w = (const unsigned int*)d_in[1];
    const float* in_w   = (const float*)d_in[2];
    const float* in_b   = (const float*)d_in[3];
    const float* ln_g   = (const float*)d_in[4];
    const float* ln_b   = (const float*)d_in[5];
    const float* dw_w   = (const float*)d_in[6];
    const float* dw_b   = (const float*)d_in[7];
    const float* win_w  = (const float*)d_in[8];
    const float* win_b  = (const float*)d_in[9];
    const float* wout_w = (const float*)d_in[10];
    const float* wout_b = (const float*)d_in[11];
    const float* fn_g   = (const float*)d_in[12];
    const float* fn_b   = (const float*)d_in[13];

    char* w8 = (char*)d_ws;
    unsigned short* wt_in   = (unsigned short*)w8;                 // 128 KB
    unsigned short* wt_win  = wt_in  + (size_t)D_ * DIN_;          // 1 MB
    unsigned short* wt_wout = wt_win + (size_t)NB_ * 2 * D_ * D_;  // 512 KB
    int* lengths = (int*)(w8 + (2u << 20));                        // 128 B
    unsigned short* wt_in_lo = (unsigned short*)(w8 + (3u << 20)); // 128 KB

    float* out0 = (float*)d_out;
    float* out1 = out0 + (size_t)ROWS_ * D_;

    k_setup<<<dim3(16, 8, 10), 256, 0, stream>>>(in_w, win_w, wout_w, mask_w,
                                                 wt_in, wt_in_lo, wt_win, wt_wout, lengths);
    k_fused<<<B_ * SEGS_, 512, 0, stream>>>(x, lengths, wt_in, wt_in_lo, in_b,
                                            ln_g, ln_b, dw_w, dw_b,
                                            wt_win, win_b, wt_wout, wout_b,
                                            fn_g, fn_b, out0, out1);
}

// Round 10
// 268.536 us; speedup vs baseline: 1.2493x; 1.1733x over previous
//
#include <hip/hip_runtime.h>
#include <math.h>

#define B_    32
#define S_    4096
#define DIN_  256
#define D_    256
#define T_    256
#define NB_   4
#define K_    5
#define EPS_  1e-5f
#define ROWS_ (B_ * T_)   // 8192

#define ORS_  16          // owned rows per block
#define CR_   32          // computed rows = owned + 8 halo each side
#define BR_   36          // buf0 rows = CR_ + 2 conv-pad rows each side
#define SEGS_ 16          // T_/ORS_
#define ASTR  264         // bf16 row stride in shorts (528 B, 16B-aligned)
#define HSTR  264         // h_lds row stride in floats (1056 B, 16B-aligned)

typedef short  shortx8  __attribute__((ext_vector_type(8)));
typedef float  floatx4  __attribute__((ext_vector_type(4)));
typedef float  floatx16 __attribute__((ext_vector_type(16)));

__device__ __forceinline__ unsigned short f2bf(float f) {
    unsigned int u = __float_as_uint(f);
    u += 0x7FFFu + ((u >> 16) & 1u);
    return (unsigned short)(u >> 16);
}
__device__ __forceinline__ float bf2f(unsigned short s) {
    return __uint_as_float((unsigned int)s << 16);
}
__device__ __forceinline__ unsigned int pack2bf(float a, float b) {
    return (unsigned int)f2bf(a) | ((unsigned int)f2bf(b) << 16);
}
__device__ __forceinline__ float bf2f_lo(unsigned int u) {
    return __uint_as_float(u << 16);
}
__device__ __forceinline__ float bf2f_hi(unsigned int u) {
    return __uint_as_float(u & 0xFFFF0000u);
}

// ---------------------------------------------------------------------------
// Setup: weight convert into MFMA-FRAGMENT order (z=0..8; z=0 also emits
// lo-plane) and batch lengths (z=9).
// Fragment order: flat = ((tile*NKK + kk)*64 + lane)*8 + j  -> a wave's
// fragment load is base + lane*16B: ONE contiguous 1KB transaction
// (was: 16B/lane at 512B row stride = 64 cache lines per instruction).
// in-proj (16x16x32): lane = ((k>>3)&3)*16 + (n&15), kk = k>>5, NKK=8.
// win/wout (32x32x16): lane = ((k>>3)&1)*32 + (n&31), kk = k>>4, NKK=16.
// ---------------------------------------------------------------------------
__global__ void k_setup(const float* __restrict__ in_w, const float* __restrict__ win_w,
                        const float* __restrict__ wout_w, const unsigned int* __restrict__ mask_w,
                        unsigned short* __restrict__ wt_in, unsigned short* __restrict__ wt_in_lo,
                        unsigned short* __restrict__ wt_win,
                        unsigned short* __restrict__ wt_wout, int* __restrict__ lengths) {
    int z = blockIdx.z;
    int tid = threadIdx.x;

    if (z == 9) {
        int b = blockIdx.y * 16 + blockIdx.x;
        if (b >= B_) return;
        __shared__ int smode;
        if (tid < 64) {                           // wave 0 only: parallel detect
            unsigned int w0 = mask_w[0];
            unsigned int vi = (tid < 32) ? mask_w[tid * 1024] : 0u;
            unsigned long long anyu8 = __ballot(vi > 1u);
            if (tid == 0) smode = (w0 == 0x3F800000u) ? 2 : (anyu8 ? 1 : 0);
        }
        __syncthreads();
        int mode = smode;
        int s = 0;
        if (mode == 0) {
            const int* m = (const int*)mask_w;
            for (int i = tid; i < S_; i += 256) s += (m[(size_t)b * S_ + i] != 0);
        } else if (mode == 2) {
            const float* m = (const float*)mask_w;
            for (int i = tid; i < S_; i += 256) s += (m[(size_t)b * S_ + i] != 0.0f);
        } else {
            const unsigned char* m = (const unsigned char*)mask_w;
            for (int i = tid; i < S_; i += 256) s += (m[(size_t)b * S_ + i] != 0);
        }
        __shared__ int sm[256];
        sm[tid] = s;
        __syncthreads();
        for (int off = 128; off > 0; off >>= 1) {
            if (tid < off) sm[tid] += sm[tid + off];
            __syncthreads();
        }
        if (tid == 0) lengths[b] = sm[0];
        return;
    }

    const float* src; unsigned short* dst; int N;
    if (z == 0)      { src = in_w;                                   dst = wt_in;                                   N = D_;     }
    else if (z <= 4) { src = win_w  + (size_t)(z - 1) * D_ * 2 * D_; dst = wt_win  + (size_t)(z - 1) * 2 * D_ * D_; N = 2 * D_; }
    else             { src = wout_w + (size_t)(z - 5) * D_ * D_;     dst = wt_wout + (size_t)(z - 5) * D_ * D_;     N = D_;     }
    int bx = blockIdx.x * 32;
    int by = blockIdx.y * 32;
    if (bx >= N) return;
    __shared__ float tile[32][33];
    int tx = tid & 31, ty = tid >> 5;
#pragma unroll
    for (int i = 0; i < 32; i += 8)
        tile[ty + i][tx] = src[(size_t)(by + ty + i) * N + bx + tx];
    __syncthreads();
#pragma unroll
    for (int i = 0; i < 32; i += 8) {
        float f = tile[tx][ty + i];
        unsigned short h = f2bf(f);
        int n = bx + ty + i, k = by + tx;
        if (z == 0) {
            int lane = ((k >> 3) & 3) * 16 + (n & 15);
            size_t idx = ((size_t)((n >> 4) * 8 + (k >> 5)) * 64 + lane) * 8 + (k & 7);
            wt_in[idx] = h;
            wt_in_lo[idx] = f2bf(f - bf2f(h));   // hi/lo split for in-proj
        } else {
            int lane = ((k >> 3) & 1) * 32 + (n & 31);
            size_t idx = ((size_t)((n >> 5) * 16 + (k >> 4)) * 64 + lane) * 8 + (k & 7);
            dst[idx] = h;
        }
    }
}

// ---------------------------------------------------------------------------
// Fully fused network: compress + in-proj + 4 conv blocks + final LN.
// One block per (batch, 16-row segment); 32 rows computed (8 halo/side).
// 512 threads, 70KB LDS. In-proj split-precision bf16 hi/lo (absmax 0.0156).
// R8 LESSON: perf invariant to occupancy/VGPR/LDS-traffic/prefetch -> the
// invariant ~140us is UNCOALESCED weight loads (16B/lane at 512B stride =
// 64 cache lines per wave-instruction through the shared TA/L1 pipe).
// THIS ROUND: weights pre-laid in fragment order; every B-operand load is
// frag_base + lane*16B = one contiguous 1KB transaction.
// ---------------------------------------------------------------------------
__global__ __launch_bounds__(512, 2) void k_fused(
    const float* __restrict__ x, const int* __restrict__ lengths,
    const unsigned short* __restrict__ wt_in, const unsigned short* __restrict__ wt_in_lo,
    const float* __restrict__ in_b,
    const float* __restrict__ ln_g, const float* __restrict__ ln_b,
    const float* __restrict__ dw_w, const float* __restrict__ dw_b,
    const unsigned short* __restrict__ wt_win, const float* __restrict__ win_b,
    const unsigned short* __restrict__ wt_wout, const float* __restrict__ wout_b,
    const float* __restrict__ fn_g, const float* __restrict__ fn_b,
    float* __restrict__ out0, float* __restrict__ out1)
{
    __shared__ unsigned short buf0[BR_][ASTR];   // 19.0 KB: x-lo plane / LN out / act
    __shared__ unsigned short buf1[CR_][ASTR];   // 16.9 KB: x-hi plane / conv out
    __shared__ float h_lds[CR_][HSTR];           // 33.8 KB: resident h (fp32)

    int tid = threadIdx.x;
    int w = tid >> 6, lane = tid & 63;
    int c16 = lane & 15, q = lane >> 4;
    int l31 = lane & 31, lh = lane >> 5;         // 32x32 fragment coords
    int b = blockIdx.x >> 4, seg = blockIdx.x & (SEGS_ - 1);
    int t0 = seg * ORS_;
    // window row r in [0,32) corresponds to t = t0 - 8 + r

    unsigned short (*xlo)[ASTR] = (unsigned short (*)[ASTR])buf0;  // rows 0..31 alias

    int L = lengths[b];

    // ---- compress -> buf1 (hi) + buf0-alias (lo), bf16, 32 rows ----
    {
        int tq = tid & 63, rg = tid >> 6;
        int col = tq * 4;
        float Lf = (float)L;
        float hi = fmaxf(Lf - 1.0f, 0.0f);
        int L1 = max(L - 1, 0);
        const float* xb = x + (size_t)b * S_ * DIN_ + col;
#pragma unroll
        for (int e = 0; e < 4; ++e) {
            int row = rg + e * 8;
            int t = t0 - 8 + row;
            t = min(max(t, 0), T_ - 1);          // out-of-range halo rows: garbage ok, masked at LN
            float src = ((float)t + 0.5f) * (Lf * (1.0f / T_)) - 0.5f;
            src = fminf(fmaxf(src, 0.0f), hi);
            int i0 = (int)floorf(src);
            int i1 = min(i0 + 1, L1);
            float wf = src - (float)i0;
            float4 v0 = *(const float4*)&xb[(size_t)i0 * DIN_];
            float4 v1 = *(const float4*)&xb[(size_t)i1 * DIN_];
            float a0 = (1.0f - wf) * v0.x + wf * v1.x;
            float a1 = (1.0f - wf) * v0.y + wf * v1.y;
            float a2 = (1.0f - wf) * v0.z + wf * v1.z;
            float a3 = (1.0f - wf) * v0.w + wf * v1.w;
            unsigned short h0 = f2bf(a0), h1 = f2bf(a1), h2 = f2bf(a2), h3 = f2bf(a3);
            uint2 oh, ol;
            oh.x = (unsigned int)h0 | ((unsigned int)h1 << 16);
            oh.y = (unsigned int)h2 | ((unsigned int)h3 << 16);
            ol.x = (unsigned int)f2bf(a0 - bf2f(h0)) | ((unsigned int)f2bf(a1 - bf2f(h1)) << 16);
            ol.y = (unsigned int)f2bf(a2 - bf2f(h2)) | ((unsigned int)f2bf(a3 - bf2f(h3)) << 16);
            *(uint2*)&buf1[row][col] = oh;
            *(uint2*)&xlo[row][col] = ol;
        }
    }
    __syncthreads();

    // ---- in-proj GEMM (split precision, fragment-ordered weights) ----
#pragma unroll
    for (int nn = 0; nn < 2; ++nn) {
        int nt = w + nn * 8;
        floatx4 acc[2] = {};
#pragma unroll
        for (int kk = 0; kk < 8; ++kk) {
            size_t fo = ((size_t)(nt * 8 + kk) << 9) + lane * 8;   // (tile*8+kk)*512 + lane*8
            shortx8 bh = *(const shortx8*)(wt_in    + fo);
            shortx8 bl = *(const shortx8*)(wt_in_lo + fo);
#pragma unroll
            for (int mt = 0; mt < 2; ++mt) {
                shortx8 ah = *(const shortx8*)&buf1[mt * 16 + c16][kk * 32 + q * 8];
                shortx8 al = *(const shortx8*)&xlo[mt * 16 + c16][kk * 32 + q * 8];
                acc[mt] = __builtin_amdgcn_mfma_f32_16x16x32_bf16(ah, bh, acc[mt], 0, 0, 0);
                acc[mt] = __builtin_amdgcn_mfma_f32_16x16x32_bf16(al, bh, acc[mt], 0, 0, 0);
                acc[mt] = __builtin_amdgcn_mfma_f32_16x16x32_bf16(ah, bl, acc[mt], 0, 0, 0);
            }
        }
        float obv = in_b[nt * 16 + c16];
#pragma unroll
        for (int mt = 0; mt < 2; ++mt)
#pragma unroll
            for (int r = 0; r < 4; ++r)
                h_lds[mt * 16 + q * 4 + r][nt * 16 + c16] = acc[mt][r] + obv;
    }
    __syncthreads();

    // zero the conv pad rows of buf0 (rows 0,1,34,35; x-lo plane is dead now;
    // disjoint from Stage A's rows 2..33, made visible by the A->B barrier)
    if (tid < 132) {
        ((unsigned int*)buf0[0])[tid] = 0u;
        ((unsigned int*)buf0[1])[tid] = 0u;
        ((unsigned int*)buf0[BR_ - 2])[tid] = 0u;
        ((unsigned int*)buf0[BR_ - 1])[tid] = 0u;
    }

    // ---- 4 conv blocks, h resident in LDS ----
    for (int li = 0; li < NB_; ++li) {
        const float* g_i = ln_g + li * D_;
        const float* b_i = ln_b + li * D_;
        const float* dww = dw_w + (size_t)li * D_ * K_;
        const float* dwb = dw_b + li * D_;
        const unsigned short* ww = wt_win + (size_t)li * 2 * D_ * D_;
        const float* wb = win_b + (size_t)li * 2 * D_;
        const unsigned short* ow = wt_wout + (size_t)li * D_ * D_;
        const float* obp = wout_b + li * D_;

        // ---- Stage A: LN h_lds -> buf0 rows 2..33 (bf16), zero out-of-range t ----
        {
            int c4 = lane * 4;
            float4 g4 = *(const float4*)&g_i[c4];
            float4 b4 = *(const float4*)&b_i[c4];
#pragma unroll
            for (int it = 0; it < 4; ++it) {
                int r = w + it * 8;
                float4 v = *(const float4*)&h_lds[r][c4];
                float s  = v.x + v.y + v.z + v.w;
                float ss = v.x * v.x + v.y * v.y + v.z * v.z + v.w * v.w;
#pragma unroll
                for (int off = 1; off < 64; off <<= 1) {
                    s += __shfl_xor(s, off);
                    ss += __shfl_xor(ss, off);
                }
                float mu = s * (1.0f / D_);
                float rsig = rsqrtf(ss * (1.0f / D_) - mu * mu + EPS_);
                uint2 o;
                o.x = pack2bf((v.x - mu) * rsig * g4.x + b4.x,
                              (v.y - mu) * rsig * g4.y + b4.y);
                o.y = pack2bf((v.z - mu) * rsig * g4.z + b4.z,
                              (v.w - mu) * rsig * g4.w + b4.w);
                int t = t0 - 8 + r;
                if (t < 0 || t >= T_) { o.x = 0; o.y = 0; }   // zero-padded conv boundary
                *(uint2*)&buf0[r + 2][c4] = o;
            }
        }
        __syncthreads();

        // ---- Stage B: depthwise conv buf0 -> buf1 (32 rows) ----
        {
            int tq = tid & 63, rg = tid >> 6;
            int col = tq * 4;
            float4 wk[K_];
#pragma unroll
            for (int k = 0; k < K_; ++k) {
                wk[k].x = dww[(col + 0) * K_ + k];
                wk[k].y = dww[(col + 1) * K_ + k];
                wk[k].z = dww[(col + 2) * K_ + k];
                wk[k].w = dww[(col + 3) * K_ + k];
            }
            float4 cb4 = *(const float4*)&dwb[col];
#pragma unroll
            for (int e = 0; e < 4; ++e) {
                int rr = rg + e * 8;
                float4 acc = cb4;
#pragma unroll
                for (int k = 0; k < K_; ++k) {
                    uint2 u = *(const uint2*)&buf0[rr + k][col];
                    acc.x += bf2f_lo(u.x) * wk[k].x;
                    acc.y += bf2f_hi(u.x) * wk[k].y;
                    acc.z += bf2f_lo(u.y) * wk[k].z;
                    acc.w += bf2f_hi(u.y) * wk[k].w;
                }
                uint2 o;
                o.x = pack2bf(acc.x, acc.y);
                o.y = pack2bf(acc.z, acc.w);
                *(uint2*)&buf1[rr][col] = o;
            }
        }
        __syncthreads();

        // ---- Stage C: win GEMM (32x512) via 32x32x16 MFMA + fused act ----
        // Wave w: gate tile w (cols w*32..+31), val tile 8+w (cols 256+w*32..).
        // One A-read per K-step feeds both tiles; B loads are coalesced
        // fragment reads (base + lane*16B).
        {
            floatx16 accG = {}, accV = {};
#pragma unroll
            for (int kk = 0; kk < 16; ++kk) {
                shortx8 a  = *(const shortx8*)&buf1[l31][kk * 16 + lh * 8];
                shortx8 bg = *(const shortx8*)(ww + ((size_t)(w * 16 + kk) << 9) + lane * 8);
                shortx8 bv = *(const shortx8*)(ww + ((size_t)((8 + w) * 16 + kk) << 9) + lane * 8);
                accG = __builtin_amdgcn_mfma_f32_32x32x16_bf16(a, bg, accG, 0, 0, 0);
                accV = __builtin_amdgcn_mfma_f32_32x32x16_bf16(a, bv, accV, 0, 0, 0);
            }
            float bg0 = wb[w * 32 + l31];
            float bv0 = wb[256 + w * 32 + l31];
#pragma unroll
            for (int r = 0; r < 16; ++r) {
                int row = (r & 3) + 8 * (r >> 2) + 4 * lh;
                float gate = accG[r] + bg0;
                float val  = accV[r] + bv0;
                float sg = 1.0f / (1.0f + __expf(-gate));
                float u = 1.5957691216f * (val + 0.044715f * val * val * val);
                float ge = val / (1.0f + __expf(-u));
                buf0[2 + row][w * 32 + l31] = f2bf(sg * ge);
            }
        }
        __syncthreads();

        // ---- Stage D: wout GEMM (32x256) via 32x32x16 + residual ----
        {
            floatx16 acc = {};
#pragma unroll
            for (int kk = 0; kk < 16; ++kk) {
                shortx8 a  = *(const shortx8*)&buf0[2 + l31][kk * 16 + lh * 8];
                shortx8 bo = *(const shortx8*)(ow + ((size_t)(w * 16 + kk) << 9) + lane * 8);
                acc = __builtin_amdgcn_mfma_f32_32x32x16_bf16(a, bo, acc, 0, 0, 0);
            }
            float bb = obp[w * 32 + l31];
#pragma unroll
            for (int r = 0; r < 16; ++r) {
                int row = (r & 3) + 8 * (r >> 2) + 4 * lh;
                int col = w * 32 + l31;
                h_lds[row][col] = h_lds[row][col] + acc[r] + bb;
            }
        }
        __syncthreads();
    }

    // ---- final LN on owned rows (8..23) -> out0; comp_mask -> out1 ----
    {
        int c4 = lane * 4;
        float4 g4 = *(const float4*)&fn_g[c4];
        float4 b4 = *(const float4*)&fn_b[c4];
#pragma unroll
        for (int it = 0; it < 2; ++it) {
            int r = 8 + w + it * 8;
            float4 v = *(const float4*)&h_lds[r][c4];
            float s  = v.x + v.y + v.z + v.w;
            float ss = v.x * v.x + v.y * v.y + v.z * v.z + v.w * v.w;
#pragma unroll
            for (int off = 1; off < 64; off <<= 1) {
                s += __shfl_xor(s, off);
                ss += __shfl_xor(ss, off);
            }
            float mu = s * (1.0f / D_);
            float rsig = rsqrtf(ss * (1.0f / D_) - mu * mu + EPS_);
            float4 o;
            o.x = (v.x - mu) * rsig * g4.x + b4.x;
            o.y = (v.y - mu) * rsig * g4.y + b4.y;
            o.z = (v.z - mu) * rsig * g4.z + b4.z;
            o.w = (v.w - mu) * rsig * g4.w + b4.w;
            *(float4*)&out0[((size_t)b * T_ + t0 + r - 8) * D_ + c4] = o;
        }
        if (tid < ORS_) out1[(size_t)b * T_ + t0 + tid] = 1.0f;
    }
}

// ---------------------------------------------------------------------------
extern "C" void kernel_launch(void* const* d_in, const int* in_sizes, int n_in,
                              void* d_out, int out_size, void* d_ws, size_t ws_size,
                              hipStream_t stream) {
    const float* x      = (const float*)d_in[0];
    const unsigned int* mask_w = (const unsigned int*)d_in[1];
    const float* in_w   = (const float*)d_in[2];
    const float* in_b   = (const float*)d_in[3];
    const float* ln_g   = (const float*)d_in[4];
    const float* ln_b   = (const float*)d_in[5];
    const float* dw_w   = (const float*)d_in[6];
    const float* dw_b   = (const float*)d_in[7];
    const float* win_w  = (const float*)d_in[8];
    const float* win_b  = (const float*)d_in[9];
    const float* wout_w = (const float*)d_in[10];
    const float* wout_b = (const float*)d_in[11];
    const float* fn_g   = (const float*)d_in[12];
    const float* fn_b   = (const float*)d_in[13];

    char* w8 = (char*)d_ws;
    unsigned short* wt_in   = (unsigned short*)w8;                 // 128 KB
    unsigned short* wt_win  = wt_in  + (size_t)D_ * DIN_;          // 1 MB
    unsigned short* wt_wout = wt_win + (size_t)NB_ * 2 * D_ * D_;  // 512 KB
    int* lengths = (int*)(w8 + (2u << 20));                        // 128 B
    unsigned short* wt_in_lo = (unsigned short*)(w8 + (3u << 20)); // 128 KB

    float* out0 = (float*)d_out;
    float* out1 = out0 + (size_t)ROWS_ * D_;

    k_setup<<<dim3(16, 8, 10), 256, 0, stream>>>(in_w, win_w, wout_w, mask_w,
                                                 wt_in, wt_in_lo, wt_win, wt_wout, lengths);
    k_fused<<<B_ * SEGS_, 512, 0, stream>>>(x, lengths, wt_in, wt_in_lo, in_b,
                                            ln_g, ln_b, dw_w, dw_b,
                                            wt_win, win_b, wt_wout, wout_b,
                                            fn_g, fn_b, out0, out1);
}